// Round 9
// baseline (508.453 us; speedup 1.0000x reference)
//
#include <hip/hip_runtime.h>
#include <math.h>
#include <stdint.h>

#define N_NODES 20000
#define N_EDGES 320000
#define H 256
#define GH 512
#define G3 768
#define NT 3
#define R_ROUNDS 2
#define MT2 79      // ceil(20000/256)
#define XW 768      // X row width (msg 512 | hv 256)
#define PW 1024     // P row width (S_rz 512 | inn 256 | hn 256)

typedef __attribute__((ext_vector_type(8))) short short8;
typedef __attribute__((ext_vector_type(8))) unsigned short ushort8;
typedef __attribute__((ext_vector_type(4))) float floatx4;

static __device__ __forceinline__ unsigned short f2bf(float x) {
  unsigned u = __float_as_uint(x);
  u += 0x7fffu + ((u >> 16) & 1u);
  return (unsigned short)(u >> 16);
}
static __device__ __forceinline__ float b2f(unsigned short x) {
  return __uint_as_float((unsigned)x << 16);
}

// async global->LDS, 16B per lane; LDS dest = wave-uniform base + lane*16
static __device__ __forceinline__ void load_lds_16(const unsigned short* g,
                                                   unsigned short* l) {
  __builtin_amdgcn_global_load_lds(
      (const __attribute__((address_space(1))) unsigned int*)g,
      (__attribute__((address_space(3))) unsigned int*)l, 16, 0, 0);
}

// ---------------------------------------------------------------- fused prep
// One launch: hv0->bf16; w_hh->bf16 (+ pack Wrz[:,512:768]); zero
// cnt/hesum/U/G/gembed; vec_comb (both rounds). Replaces 3 kernels + memsets.
#define PB_HV 2500   // 5,120,000 elems / 2048
#define PB_WHH 192   // 393,216 elems / 2048
#define PB_CNT 10
#define PB_HES 10
#define PB_BASE (PB_HV + PB_WHH + PB_CNT + PB_HES)
#define PB_VEC 384   // 2*G3/4
#define PREP_GRID (PB_BASE + 2 + PB_VEC)

__global__ __launch_bounds__(256) void prep_kernel(
    const float* __restrict__ hv0, const float* __restrict__ w_hh,
    unsigned short* __restrict__ HVb, unsigned short* __restrict__ whhb,
    unsigned short* __restrict__ Wrz, int* __restrict__ cnt,
    float* __restrict__ hesum, float* __restrict__ U, float* __restrict__ ge,
    const float* __restrict__ msg_w, const float* __restrict__ msg_b,
    const float* __restrict__ w_ih, float* __restrict__ wep,
    float* __restrict__ bmp) {
  int b = blockIdx.x, tid = threadIdx.x;
  if (b < PB_HV) {
    int idx = (b * 256 + tid) * 8;
    const float* p = hv0 + idx;
    float4 v0 = *(const float4*)p;
    float4 v1 = *(const float4*)(p + 4);
    ushort8 o;
    o[0] = f2bf(v0.x); o[1] = f2bf(v0.y); o[2] = f2bf(v0.z); o[3] = f2bf(v0.w);
    o[4] = f2bf(v1.x); o[5] = f2bf(v1.y); o[6] = f2bf(v1.z); o[7] = f2bf(v1.w);
    *(ushort8*)(HVb + idx) = o;
  } else if (b < PB_HV + PB_WHH) {
    int idx = ((b - PB_HV) * 256 + tid) * 8;
    const float* p = w_hh + idx;
    float4 v0 = *(const float4*)p;
    float4 v1 = *(const float4*)(p + 4);
    ushort8 o;
    o[0] = f2bf(v0.x); o[1] = f2bf(v0.y); o[2] = f2bf(v0.z); o[3] = f2bf(v0.w);
    o[4] = f2bf(v1.x); o[5] = f2bf(v1.y); o[6] = f2bf(v1.z); o[7] = f2bf(v1.w);
    *(ushort8*)(whhb + idx) = o;
    int t = idx / (G3 * H);
    int rem = idx % (G3 * H);
    int n = rem / H, k = rem % H;  // 8-elem chunk stays within one row (H%8==0)
    if (n < 512)
      *(ushort8*)(Wrz + (size_t)t * 512 * XW + (size_t)n * XW + GH + k) = o;
  } else if (b < PB_HV + PB_WHH + PB_CNT) {
    int idx = ((b - PB_HV - PB_WHH) * 256 + tid) * 8;
#pragma unroll
    for (int j = 0; j < 8; j++)
      if (idx + j < N_NODES) cnt[idx + j] = 0;
  } else if (b < PB_BASE) {
    int idx = ((b - PB_HV - PB_WHH - PB_CNT) * 256 + tid) * 8;
#pragma unroll
    for (int j = 0; j < 8; j++)
      if (idx + j < N_NODES) hesum[idx + j] = 0.f;
  } else if (b == PB_BASE) {
    for (int i = tid; i < NT * H + NT; i += 256) U[i] = 0.f;
  } else if (b == PB_BASE + 1) {
    for (int i = tid; i < GH + 4 + H + 1; i += 256) ge[i] = 0.f;
  } else {
    // vec_comb: wep[ng]=dot(msg_w row512, w_ih[n]); bmp[ng]=dot(msg_b, w_ih[n])
    int vb = b - (PB_BASE + 2);
    int ng = vb * 4 + (tid >> 6);
    int t = ng / G3, n = ng % G3;
    int lane = tid & 63;
    const float* we = msg_w + (size_t)t * 513 * 512 + (size_t)GH * GH;
    const float* mb = msg_b + (size_t)t * GH;
    const float* wr = w_ih + (size_t)t * G3 * GH + (size_t)n * GH;
    float s1 = 0.f, s2 = 0.f;
    for (int k = lane; k < GH; k += 64) {
      float w = wr[k];
      s1 += we[k] * w;
      s2 += mb[k] * w;
    }
    for (int off = 32; off; off >>= 1) {
      s1 += __shfl_xor(s1, off);
      s2 += __shfl_xor(s2, off);
    }
    if (lane == 0) {
      wep[ng] = s1;
      bmp[ng] = s2;
    }
  }
}

// ---------------------------------------------------------------- CSR build
__global__ __launch_bounds__(256) void hist_kernel(
    const int* __restrict__ dst, const float* __restrict__ he,
    int* __restrict__ cnt, float* __restrict__ hesum) {
  int e = blockIdx.x * 256 + threadIdx.x;
  if (e >= N_EDGES) return;
  int d = dst[e];
  atomicAdd(&cnt[d], 1);
  unsafeAtomicAdd(&hesum[d], he[e]);
}

__global__ __launch_bounds__(1024) void scan_kernel(
    const int* __restrict__ cnt, int* __restrict__ rowptr, int* __restrict__ cursor) {
  __shared__ int part[1024];
  const int CH = (N_NODES + 1023) / 1024;  // 20
  int t = threadIdx.x;
  int base = t * CH;
  int s = 0;
  for (int j = 0; j < CH; j++) {
    int idx = base + j;
    if (idx < N_NODES) s += cnt[idx];
  }
  part[t] = s;
  __syncthreads();
  int v = part[t];
  for (int off = 1; off < 1024; off <<= 1) {
    int o = (t >= off) ? part[t - off] : 0;
    __syncthreads();
    part[t] += o;
    __syncthreads();
  }
  int excl = part[t] - v;
  int run = excl;
  for (int j = 0; j < CH; j++) {
    int idx = base + j;
    if (idx < N_NODES) {
      rowptr[idx] = run;
      cursor[idx] = run;
      run += cnt[idx];
    }
  }
  if (t == 1023) rowptr[N_NODES] = run;
}

__global__ __launch_bounds__(256) void fill_kernel(
    const int* __restrict__ dst, const int* __restrict__ src,
    int* __restrict__ cursor, int* __restrict__ nbr) {
  int e = blockIdx.x * 256 + threadIdx.x;
  if (e >= N_EDGES) return;
  int p = atomicAdd(&cursor[dst[e]], 1);
  nbr[p] = src[e];
}

// ---------------------------------------------------------------- gather (bf16 reads)
__global__ __launch_bounds__(256) void gather_kernel(
    const unsigned short* __restrict__ hvb, const int* __restrict__ rowptr,
    const int* __restrict__ nbr, unsigned short* __restrict__ X,
    float* __restrict__ deg) {
  int w = (blockIdx.x * blockDim.x + threadIdx.x) >> 6;
  int lane = threadIdx.x & 63;
  if (w >= N_NODES) return;
  int start = rowptr[w], end = rowptr[w + 1];
  float4 acc = make_float4(0.f, 0.f, 0.f, 0.f);
  for (int b = start; b < end; b += 64) {
    int nb = min(64, end - b);
    int sidx = (lane < nb) ? nbr[b + lane] : 0;
    int j = 0;
    for (; j + 8 <= nb; j += 8) {
      ushort4 u[8];
#pragma unroll
      for (int q = 0; q < 8; q++) {
        int s = __shfl(sidx, j + q);
        u[q] = *reinterpret_cast<const ushort4*>(hvb + (size_t)s * H + lane * 4);
      }
#pragma unroll
      for (int q = 0; q < 8; q++) {
        acc.x += b2f(u[q].x);
        acc.y += b2f(u[q].y);
        acc.z += b2f(u[q].z);
        acc.w += b2f(u[q].w);
      }
    }
    for (; j < nb; j++) {
      int s = __shfl(sidx, j);
      ushort4 u = *reinterpret_cast<const ushort4*>(hvb + (size_t)s * H + lane * 4);
      acc.x += b2f(u.x); acc.y += b2f(u.y); acc.z += b2f(u.z); acc.w += b2f(u.w);
    }
  }
  float dg = (float)(end - start);
  ushort4 uo = *reinterpret_cast<const ushort4*>(hvb + (size_t)w * H + lane * 4);
  float ox = b2f(uo.x), oy = b2f(uo.y), oz = b2f(uo.z), ow = b2f(uo.w);
  ushort4 o;
  o.x = f2bf(ox * dg); o.y = f2bf(oy * dg);
  o.z = f2bf(oz * dg); o.w = f2bf(ow * dg);
  *reinterpret_cast<ushort4*>(X + (size_t)w * XW + lane * 4) = o;
  o.x = f2bf(acc.x); o.y = f2bf(acc.y); o.z = f2bf(acc.z); o.w = f2bf(acc.w);
  *reinterpret_cast<ushort4*>(X + (size_t)w * XW + H + lane * 4) = o;
  *reinterpret_cast<ushort4*>(X + (size_t)w * XW + GH + lane * 4) = uo;
  if (lane == 0) deg[w] = dg;
}

// ---------------------------------------------------------------- GEMM pieces
// XOR chunk layout (v0): LDS[row][p] holds global chunk (p ^ (row&7)) of row.
#define MFMA_BLOCK                                                                \
  _Pragma("unroll") for (int kk = 0; kk < 2; kk++) {                              \
    short8 af[4], bf[4];                                                          \
    _Pragma("unroll") for (int mi = 0; mi < 4; mi++) {                            \
      int row = m0 + mi * 16 + lr;                                                \
      af[mi] = *(const short8*)(As + row * 64 + ((kk * 4 + lq) ^ (row & 7)) * 8); \
    }                                                                             \
    _Pragma("unroll") for (int ni = 0; ni < 4; ni++) {                            \
      int row = n0 + ni * 16 + lr;                                                \
      bf[ni] = *(const short8*)(Bs + row * 64 + ((kk * 4 + lq) ^ (row & 7)) * 8); \
    }                                                                             \
    _Pragma("unroll") for (int mi = 0; mi < 4; mi++)                              \
      _Pragma("unroll") for (int ni = 0; ni < 4; ni++)                            \
        acc[mi][ni] = __builtin_amdgcn_mfma_f32_16x16x32_bf16(af[mi], bf[ni],     \
                                                              acc[mi][ni], 0, 0, 0); \
  }

// 8-wave staging: A-tile 256x64, B-tile 128x64 (48 KB total).
static __device__ __forceinline__ void stage_tile_256(
    const unsigned short* gA, int lda, const unsigned short* gB, int ldb,
    unsigned short* As, unsigned short* Bs,
    size_t i0, size_t j0, int k0, int wv, int lane) {
  int rsub = lane >> 3;
  int pos = lane & 7;
#pragma unroll
  for (int q = 0; q < 4; q++) {
    int row = wv * 32 + q * 8 + rsub;
    int gc = (pos ^ (row & 7)) * 8;
    load_lds_16(gA + (i0 + row) * (size_t)lda + k0 + gc, As + (wv * 32 + q * 8) * 64);
  }
#pragma unroll
  for (int q = 0; q < 2; q++) {
    int row = wv * 16 + q * 8 + rsub;
    int gc = (pos ^ (row & 7)) * 8;
    load_lds_16(gB + (j0 + row) * (size_t)ldb + k0 + gc, Bs + (wv * 16 + q * 8) * 64);
  }
}

#define GEMM_CORE_256(A, lda, W, ldb, K)                                          \
  {                                                                               \
    stage_tile_256((A), (lda), (W), (ldb), As, Bs, i0, j0, 0, wv, lane);          \
    for (int k0 = 0; k0 < (K); k0 += 64) {                                        \
      __syncthreads();                                                            \
      MFMA_BLOCK                                                                  \
      if (k0 + 64 < (K)) {                                                        \
        __syncthreads();                                                          \
        stage_tile_256((A), (lda), (W), (ldb), As, Bs, i0, j0, k0 + 64, wv, lane);\
      }                                                                           \
    }                                                                             \
  }

// ---------------------------------------------------------------- weight-combine GEMM
// Reads f32 weights directly (reg-stage -> bf16 -> ds_write, same XOR layout).
// Both rounds in one launch: grid (4, 6, 2). Epilogue writes Wc and Wrz[:, :512].
static __device__ __forceinline__ void wstage_f32(
    const float* gA, const float* gB, unsigned short* As, unsigned short* Bs,
    size_t i0, size_t j0, int k0, int wv, int lane) {
  int rsub = lane >> 3;
  int pos = lane & 7;
#pragma unroll
  for (int q = 0; q < 4; q++) {
    int row = wv * 32 + q * 8 + rsub;
    int gc = (pos ^ (row & 7)) * 8;
    const float* pa = gA + (i0 + row) * (size_t)GH + k0 + gc;
    const float* pb = gB + (j0 + row) * (size_t)GH + k0 + gc;
    float4 a0 = *(const float4*)pa;
    float4 a1 = *(const float4*)(pa + 4);
    float4 b0 = *(const float4*)pb;
    float4 b1 = *(const float4*)(pb + 4);
    ushort8 ua, ub;
    ua[0] = f2bf(a0.x); ua[1] = f2bf(a0.y); ua[2] = f2bf(a0.z); ua[3] = f2bf(a0.w);
    ua[4] = f2bf(a1.x); ua[5] = f2bf(a1.y); ua[6] = f2bf(a1.z); ua[7] = f2bf(a1.w);
    ub[0] = f2bf(b0.x); ub[1] = f2bf(b0.y); ub[2] = f2bf(b0.z); ub[3] = f2bf(b0.w);
    ub[4] = f2bf(b1.x); ub[5] = f2bf(b1.y); ub[6] = f2bf(b1.z); ub[7] = f2bf(b1.w);
    *(ushort8*)(As + row * 64 + pos * 8) = ua;
    *(ushort8*)(Bs + row * 64 + pos * 8) = ub;
  }
}

__global__ __launch_bounds__(256) void wcomb_gemm(
    const float* __restrict__ w_ih, const float* __restrict__ msg_w,
    unsigned short* __restrict__ Wc, unsigned short* __restrict__ Wrz) {
  __shared__ alignas(16) unsigned short As[128 * 64];
  __shared__ alignas(16) unsigned short Bs[128 * 64];
  int t = threadIdx.x;
  int rt = blockIdx.z;
  const float* A = w_ih + (size_t)rt * G3 * GH;
  const float* W = msg_w + (size_t)rt * 513 * 512;
  unsigned short* Cb = Wc + (size_t)rt * G3 * GH;
  unsigned short* Rz = Wrz + (size_t)rt * 512 * XW;
  size_t i0 = (size_t)blockIdx.y * 128;
  size_t j0 = (size_t)blockIdx.x * 128;
  int wv = t >> 6, lane = t & 63;
  int m0 = (wv >> 1) * 64, n0 = (wv & 1) * 64;
  int lr = lane & 15, lq = lane >> 4;
  floatx4 acc[4][4];
#pragma unroll
  for (int a = 0; a < 4; a++)
#pragma unroll
    for (int b = 0; b < 4; b++) acc[a][b] = (floatx4){0.f, 0.f, 0.f, 0.f};
  {
    wstage_f32(A, W, As, Bs, i0, j0, 0, wv, lane);
    for (int k0 = 0; k0 < GH; k0 += 64) {
      __syncthreads();
      MFMA_BLOCK
      if (k0 + 64 < GH) {
        __syncthreads();
        wstage_f32(A, W, As, Bs, i0, j0, k0 + 64, wv, lane);
      }
    }
  }
#pragma unroll
  for (int mi = 0; mi < 4; mi++) {
#pragma unroll
    for (int ni = 0; ni < 4; ni++) {
      int col = (int)j0 + n0 + ni * 16 + lr;
#pragma unroll
      for (int i = 0; i < 4; i++) {
        size_t row = i0 + m0 + mi * 16 + lq * 4 + i;
        unsigned short v = f2bf(acc[mi][ni][i]);
        Cb[row * GH + col] = v;
        if (row < 512) Rz[row * XW + col] = v;
      }
    }
  }
}

// ---------------------------------------------------------------- fused gate GEMM
// BM=256 x BN=128, 8 waves (512 thr), 48 KB LDS, proven 2-barrier schedule.
// Grid 640 = 8 XCD x 10 x 8 jb (8 idle). Per row-tile it (256 rows), jb slots:
//  jb 0..3: S_rz = X @ Wrz^T (K=768), out cols [0,512)
//  jb 4..5: inn  = Xmsg @ Wc_n^T (K=512), out [512,768)
//  jb 6..7: hn   = Xhv @ Whh_n^T (K=256), out [768,1024)
__global__ __launch_bounds__(512) void gate_gemm(
    const unsigned short* __restrict__ X, const unsigned short* __restrict__ Wrz,
    const unsigned short* __restrict__ Wc_t, const unsigned short* __restrict__ Whh_t,
    const float* __restrict__ wep, const float* __restrict__ bmp,
    const float* __restrict__ bih, const float* __restrict__ bhh,
    const float* __restrict__ deg, const float* __restrict__ hesum,
    unsigned short* __restrict__ P) {
  __shared__ alignas(16) unsigned short As[256 * 64];
  __shared__ alignas(16) unsigned short Bs[128 * 64];
  int bid = blockIdx.x;
  int xk = bid & 7, sl = bid >> 3;  // sl in [0,80)
  int it = xk * 10 + (sl >> 3);
  if (it >= MT2) return;
  int jb = sl & 7;
  int t = threadIdx.x;
  size_t i0 = (size_t)it * 256;
  size_t j0 = 0;
  int wv = t >> 6, lane = t & 63;
  int m0 = (wv >> 1) * 64, n0 = (wv & 1) * 64;
  int lr = lane & 15, lq = lane >> 4;
  floatx4 acc[4][4];
#pragma unroll
  for (int a = 0; a < 4; a++)
#pragma unroll
    for (int b = 0; b < 4; b++) acc[a][b] = (floatx4){0.f, 0.f, 0.f, 0.f};

  const unsigned short* Abase;
  const unsigned short* Bbase;
  int K, ldb, ocol0;
  if (jb < 4) {
    Abase = X; K = XW; Bbase = Wrz + (size_t)(jb * 128) * XW; ldb = XW;
    ocol0 = jb * 128;
  } else if (jb < 6) {
    Abase = X; K = GH; Bbase = Wc_t + (size_t)(512 + (jb - 4) * 128) * GH; ldb = GH;
    ocol0 = 512 + (jb - 4) * 128;
  } else {
    Abase = X + GH; K = H; Bbase = Whh_t + (size_t)(512 + (jb - 6) * 128) * H; ldb = H;
    ocol0 = 768 + (jb - 6) * 128;
  }
  GEMM_CORE_256(Abase, XW, Bbase, ldb, K)

  bool add_gi = (jb < 6);
  bool add_hh = (jb < 4) || (jb >= 6);
  int g3base = (jb >= 6) ? (ocol0 - 256) : ocol0;
#pragma unroll
  for (int mi = 0; mi < 4; mi++) {
#pragma unroll
    for (int ni = 0; ni < 4; ni++) {
      int oc = ocol0 + n0 + ni * 16 + lr;
      int gc = g3base + n0 + ni * 16 + lr;
      float badd = 0.f, wv_ = 0.f, bv = 0.f;
      if (add_gi) { badd += bih[gc]; wv_ = wep[gc]; bv = bmp[gc]; }
      if (add_hh) badd += bhh[gc];
#pragma unroll
      for (int i = 0; i < 4; i++) {
        size_t row = i0 + m0 + mi * 16 + lq * 4 + i;
        if (row < (size_t)N_NODES)
          P[row * PW + oc] =
              f2bf(acc[mi][ni][i] + hesum[row] * wv_ + deg[row] * bv + badd);
      }
    }
  }
}

// ---------------------------------------------------------------- GRU elementwise
// r = sig(S[c]), z = sig(S[c+256]), n = tanh(inn[c] + r*hn[c]); h' = (1-z)n + z h
// On the final round also computes gate sigmoid + dest scores from hvv in-reg.
__global__ __launch_bounds__(256) void gru_update(
    const unsigned short* __restrict__ P, const float* __restrict__ hvin,
    float* __restrict__ hvout, unsigned short* __restrict__ hvb, int do_heads,
    const int* __restrict__ ntype, const float* __restrict__ gate_w,
    const float* __restrict__ gate_b, const float* __restrict__ dest_w,
    float* __restrict__ gw, float* __restrict__ scores) {
  int idx = blockIdx.x * 256 + threadIdx.x;
  if (idx >= N_NODES * 32) return;
  int row = idx >> 5;
  int c8 = (idx & 31) << 3;
  const unsigned short* pr = P + (size_t)row * PW;
  ushort8 vsr = *(const ushort8*)(pr + c8);
  ushort8 vsz = *(const ushort8*)(pr + 256 + c8);
  ushort8 vin = *(const ushort8*)(pr + 512 + c8);
  ushort8 vhn = *(const ushort8*)(pr + 768 + c8);
  const float* hp = hvin + (size_t)row * H + c8;
  float4 h0 = *(const float4*)hp;
  float4 h1 = *(const float4*)(hp + 4);
  float hvv[8] = {h0.x, h0.y, h0.z, h0.w, h1.x, h1.y, h1.z, h1.w};
  ushort8 ob;
#pragma unroll
  for (int j = 0; j < 8; j++) {
    float r = 1.f / (1.f + expf(-b2f(vsr[j])));
    float z = 1.f / (1.f + expf(-b2f(vsz[j])));
    float n = tanhf(b2f(vin[j]) + r * b2f(vhn[j]));
    hvv[j] = (1.f - z) * n + z * hvv[j];
    ob[j] = f2bf(hvv[j]);
  }
  float* op = hvout + (size_t)row * H + c8;
  *(float4*)op = make_float4(hvv[0], hvv[1], hvv[2], hvv[3]);
  *(float4*)(op + 4) = make_float4(hvv[4], hvv[5], hvv[6], hvv[7]);
  *(ushort8*)(hvb + (size_t)row * H + c8) = ob;
  if (do_heads) {
    int tg = ntype[row];
    const float* gwp = gate_w + tg * H + c8;
    const float* dwp = dest_w + c8;
    float sg = 0.f, sd = 0.f;
#pragma unroll
    for (int j = 0; j < 8; j++) {
      sg += hvv[j] * gwp[j];
      sd += hvv[j] * dwp[j];
    }
    // reduce over the 32 lanes owning this row (xor<32 stays within the half)
    for (int off = 16; off; off >>= 1) {
      sg += __shfl_xor(sg, off);
      sd += __shfl_xor(sd, off);
    }
    if ((threadIdx.x & 31) == 0) {
      gw[row] = 1.f / (1.f + expf(-(sg + gate_b[tg])));
      if (row < N_NODES - 1) scores[row] = sd;
    }
  }
}

// ---------------------------------------------------------------- U column-sum
__global__ __launch_bounds__(256) void usum_kernel(
    const float* __restrict__ hv, const int* __restrict__ ntype,
    const float* __restrict__ gw, float* __restrict__ U, float* __restrict__ G) {
  const int CH = (N_NODES + 255) / 256;  // 79
  int col = threadIdx.x;
  int r0 = blockIdx.x * CH;
  int r1 = min(r0 + CH, N_NODES);
  float a0 = 0.f, a1 = 0.f, a2 = 0.f;
  float g0 = 0.f, g1 = 0.f, g2 = 0.f;
  int i = r0;
  for (; i + 4 <= r1; i += 4) {
    float v0 = hv[(size_t)(i + 0) * H + col];
    float v1 = hv[(size_t)(i + 1) * H + col];
    float v2 = hv[(size_t)(i + 2) * H + col];
    float v3 = hv[(size_t)(i + 3) * H + col];
    int t0 = ntype[i + 0], t1 = ntype[i + 1], t2 = ntype[i + 2], t3 = ntype[i + 3];
    float w0 = gw[i + 0], w1 = gw[i + 1], w2 = gw[i + 2], w3 = gw[i + 3];
    v0 *= w0; v1 *= w1; v2 *= w2; v3 *= w3;
    a0 += (t0 == 0) ? v0 : 0.f; a1 += (t0 == 1) ? v0 : 0.f; a2 += (t0 == 2) ? v0 : 0.f;
    a0 += (t1 == 0) ? v1 : 0.f; a1 += (t1 == 1) ? v1 : 0.f; a2 += (t1 == 2) ? v1 : 0.f;
    a0 += (t2 == 0) ? v2 : 0.f; a1 += (t2 == 1) ? v2 : 0.f; a2 += (t2 == 2) ? v2 : 0.f;
    a0 += (t3 == 0) ? v3 : 0.f; a1 += (t3 == 1) ? v3 : 0.f; a2 += (t3 == 2) ? v3 : 0.f;
    g0 += (t0 == 0) ? w0 : 0.f; g1 += (t0 == 1) ? w0 : 0.f; g2 += (t0 == 2) ? w0 : 0.f;
    g0 += (t1 == 0) ? w1 : 0.f; g1 += (t1 == 1) ? w1 : 0.f; g2 += (t1 == 2) ? w1 : 0.f;
    g0 += (t2 == 0) ? w2 : 0.f; g1 += (t2 == 1) ? w2 : 0.f; g2 += (t2 == 2) ? w2 : 0.f;
    g0 += (t3 == 0) ? w3 : 0.f; g1 += (t3 == 1) ? w3 : 0.f; g2 += (t3 == 2) ? w3 : 0.f;
  }
  for (; i < r1; i++) {
    float v = hv[(size_t)i * H + col];
    int t = ntype[i];
    float w = gw[i];
    v *= w;
    a0 += (t == 0) ? v : 0.f; a1 += (t == 1) ? v : 0.f; a2 += (t == 2) ? v : 0.f;
    g0 += (t == 0) ? w : 0.f; g1 += (t == 1) ? w : 0.f; g2 += (t == 2) ? w : 0.f;
  }
  unsafeAtomicAdd(&U[0 * H + col], a0);
  unsafeAtomicAdd(&U[1 * H + col], a1);
  unsafeAtomicAdd(&U[2 * H + col], a2);
  if (col == 0) {
    unsafeAtomicAdd(&G[0], g0);
    unsafeAtomicAdd(&G[1], g1);
    unsafeAtomicAdd(&G[2], g2);
  }
}

// ---------------------------------------------------------------- gembed (k-split, MLP)
__global__ __launch_bounds__(256) void gembed_partial(
    const float* __restrict__ U, const float* __restrict__ G,
    const float* __restrict__ tograph_w, const float* __restrict__ tograph_b,
    float* __restrict__ gembed_out) {
  int b = blockIdx.x;
  int t = b >> 4, half = (b >> 3) & 1, kc = b & 7;
  int col = half * 256 + threadIdx.x;
  int k0 = kc * 32;
  const float* Wt = tograph_w + (size_t)t * H * GH;
  float w[32], u[32];
#pragma unroll
  for (int j = 0; j < 32; j++) w[j] = Wt[(size_t)(k0 + j) * GH + col];
#pragma unroll
  for (int j = 0; j < 32; j++) u[j] = U[t * H + k0 + j];
  float acc = (kc == 0) ? G[t] * tograph_b[t * GH + col] : 0.f;
#pragma unroll
  for (int j = 0; j < 32; j++) acc += u[j] * w[j];
  unsafeAtomicAdd(&gembed_out[col], acc);
}

// ---------------------------------------------------------------- heads (+ dest softmax)
__global__ __launch_bounds__(256) void heads_kernel(
    const float* __restrict__ ge, const float* __restrict__ addnode_w,
    const float* __restrict__ addnode_b, const float* __restrict__ ntype_embed,
    const float* __restrict__ inithv_w, const float* __restrict__ inithv_b,
    const float* __restrict__ addedge_w, const float* __restrict__ addedge_b,
    const float* __restrict__ hv, float* __restrict__ nodelogp_out,
    float* __restrict__ hvinit_out, float* __restrict__ edgelogit_out,
    const float* __restrict__ scores, float* __restrict__ destlogp_out) {
  int b = blockIdx.x;
  int tid = threadIdx.x;
  if (b < 24) {
    int k0 = b * 32;
    float w[32], x[32];
#pragma unroll
    for (int j = 0; j < 32; j++) w[j] = inithv_w[(size_t)(k0 + j) * H + tid];
#pragma unroll
    for (int j = 0; j < 32; j++) {
      int k = k0 + j;
      x[j] = (k < H) ? ntype_embed[k] : ge[k - H];
    }
    float acc = (b == 0) ? inithv_b[tid] : 0.f;
#pragma unroll
    for (int j = 0; j < 32; j++) acc += x[j] * w[j];
    unsafeAtomicAdd(&hvinit_out[tid], acc);
  } else if (b == 24) {
    __shared__ float lg[4];
    int w = tid >> 6, lane = tid & 63;
    float s = 0.f;
    for (int k = lane; k < GH; k += 64) s += ge[k] * addnode_w[k * 4 + w];
    for (int off = 32; off; off >>= 1) s += __shfl_xor(s, off);
    if (lane == 0) lg[w] = s + addnode_b[w];
    __syncthreads();
    if (tid == 0) {
      float m = fmaxf(fmaxf(lg[0], lg[1]), fmaxf(lg[2], lg[3]));
      float sum = 0.f;
      for (int c = 0; c < 4; c++) sum += expf(lg[c] - m);
      float lse = m + logf(sum);
      for (int c = 0; c < 4; c++) nodelogp_out[c] = lg[c] - lse;
    }
  } else if (b == 25) {
    int w = tid >> 6, lane = tid & 63;
    if (w == 0) {
      const float* se = hv + (size_t)(N_NODES - 1) * H;
      float s = 0.f;
      for (int k = lane; k < G3; k += 64) {
        float x = (k < GH) ? ge[k] : se[k - GH];
        s += x * addedge_w[k];
      }
      for (int off = 32; off; off >>= 1) s += __shfl_xor(s, off);
      if (lane == 0) edgelogit_out[0] = s + addedge_b[0];
    }
  } else {
    // dest log_softmax over scores[0 .. N-2], 256 threads
    __shared__ float red[4];
    __shared__ float bc[2];
    const int n = N_NODES - 1;
    float m = -1e30f;
    for (int i = tid; i < n; i += 256) m = fmaxf(m, scores[i]);
    for (int off = 32; off; off >>= 1) m = fmaxf(m, __shfl_xor(m, off));
    if ((tid & 63) == 0) red[tid >> 6] = m;
    __syncthreads();
    if (tid == 0)
      bc[0] = fmaxf(fmaxf(red[0], red[1]), fmaxf(red[2], red[3]));
    __syncthreads();
    float mx = bc[0];
    float s = 0.f;
    for (int i = tid; i < n; i += 256) s += expf(scores[i] - mx);
    for (int off = 32; off; off >>= 1) s += __shfl_xor(s, off);
    if ((tid & 63) == 0) red[tid >> 6] = s;
    __syncthreads();
    if (tid == 0) bc[1] = red[0] + red[1] + red[2] + red[3];
    __syncthreads();
    float lse = mx + logf(bc[1]);
    for (int i = tid; i < n; i += 256) destlogp_out[i] = scores[i] - lse;
  }
}

// ---------------------------------------------------------------- launch
extern "C" void kernel_launch(void* const* d_in, const int* in_sizes, int n_in,
                              void* d_out, int out_size, void* d_ws, size_t ws_size,
                              hipStream_t stream) {
  const float* hv0 = (const float*)d_in[0];
  const float* he = (const float*)d_in[1];
  const int* ntype = (const int*)d_in[2];
  const int* src = (const int*)d_in[3];
  const int* dst = (const int*)d_in[4];
  const float* msg_w = (const float*)d_in[5];
  const float* msg_b = (const float*)d_in[6];
  const float* w_ih = (const float*)d_in[7];
  const float* b_ih = (const float*)d_in[8];
  const float* w_hh = (const float*)d_in[9];
  const float* b_hh = (const float*)d_in[10];
  const float* gate_w = (const float*)d_in[11];
  const float* gate_b = (const float*)d_in[12];
  const float* tograph_w = (const float*)d_in[13];
  const float* tograph_b = (const float*)d_in[14];
  const float* addnode_w = (const float*)d_in[15];
  const float* addnode_b = (const float*)d_in[16];
  const float* ntype_embed = (const float*)d_in[17];
  const float* inithv_w = (const float*)d_in[18];
  const float* inithv_b = (const float*)d_in[19];
  const float* addedge_w = (const float*)d_in[20];
  const float* addedge_b = (const float*)d_in[21];
  const float* dest_w = (const float*)d_in[22];
  const float* dest_b = (const float*)d_in[23];

  float* out = (float*)d_out;
  float* HV = out;
  float* gembed_out = out + (size_t)N_NODES * H;
  float* nodelogp_out = gembed_out + GH;
  float* hvinit_out = nodelogp_out + 4;
  float* edgelogit_out = hvinit_out + H;
  float* destlogp_out = edgelogit_out + 1;

  float* ws = (float*)d_ws;
  float* deg = ws;                                    // N
  float* hesum = deg + N_NODES;                       // N
  float* U = hesum + N_NODES;                         // NT*H
  float* G = U + NT * H;                              // NT
  float* misc = G + NT;                               // 16
  float* wep = misc + 16;                             // 2*G3
  float* bmp = wep + 2 * G3;                          // 2*G3
  float* scores = bmp + 2 * G3;                       // N
  float* gw = scores + N_NODES;                       // N
  int* cnt = (int*)(gw + N_NODES);                    // N
  int* rowptr = cnt + N_NODES;                        // N+1
  int* cursor = rowptr + N_NODES + 1;                 // N
  int* nbr = cursor + N_NODES;                        // E
  unsigned short* X =
      (unsigned short*)(((uintptr_t)(nbr + N_EDGES) + 15) & ~(uintptr_t)15);
  unsigned short* P = X + (size_t)(N_NODES + 256) * XW;  // X padded for BM=256 tail
  unsigned short* HVb = P + (size_t)(N_NODES + 128) * PW;
  unsigned short* whhb = HVb + (size_t)(N_NODES + 128) * H;
  unsigned short* Wc = whhb + (size_t)2 * G3 * H;      // 2 * G3*GH
  unsigned short* Wrz = Wc + (size_t)2 * G3 * GH;      // 2 * 512*768

  // ---- fused prep: casts + pack + zeroing + vec_comb
  prep_kernel<<<PREP_GRID, 256, 0, stream>>>(hv0, w_hh, HVb, whhb, Wrz, cnt,
                                             hesum, U, gembed_out, msg_w, msg_b,
                                             w_ih, wep, bmp);
  // weight-combine (reads f32 directly, both rounds in one launch)
  wcomb_gemm<<<dim3(GH / 128, G3 / 128, 2), 256, 0, stream>>>(w_ih, msg_w, Wc, Wrz);

  // ---- CSR build
  hist_kernel<<<(N_EDGES + 255) / 256, 256, 0, stream>>>(dst, he, cnt, hesum);
  scan_kernel<<<1, 1024, 0, stream>>>(cnt, rowptr, cursor);
  fill_kernel<<<(N_EDGES + 255) / 256, 256, 0, stream>>>(dst, src, cursor, nbr);

  for (int t = 0; t < R_ROUNDS; t++) {
    gather_kernel<<<N_NODES / 4, 256, 0, stream>>>(HVb, rowptr, nbr, X, deg);
    gate_gemm<<<640, 512, 0, stream>>>(
        X, Wrz + (size_t)t * 512 * XW, Wc + (size_t)t * G3 * GH,
        whhb + (size_t)t * G3 * H, wep + (size_t)t * G3, bmp + (size_t)t * G3,
        b_ih + (size_t)t * G3, b_hh + (size_t)t * G3, deg, hesum, P);
    gru_update<<<(N_NODES * 32 + 255) / 256, 256, 0, stream>>>(
        P, (t == 0) ? hv0 : HV, HV, HVb, (t == R_ROUNDS - 1) ? 1 : 0, ntype,
        gate_w, gate_b, dest_w, gw, scores);
  }

  // ---- graph embed + heads (dest softmax folded into heads_kernel b==26)
  usum_kernel<<<256, 256, 0, stream>>>(HV, ntype, gw, U, G);
  gembed_partial<<<48, 256, 0, stream>>>(U, G, tograph_w, tograph_b, gembed_out);
  heads_kernel<<<27, 256, 0, stream>>>(gembed_out, addnode_w, addnode_b, ntype_embed,
                                       inithv_w, inithv_b, addedge_w, addedge_b, HV,
                                       nodelogp_out, hvinit_out, edgelogit_out,
                                       scores, destlogp_out);
}

// Round 10
// 483.845 us; speedup vs baseline: 1.0509x; 1.0509x over previous
//
#include <hip/hip_runtime.h>
#include <math.h>
#include <stdint.h>

#define N_NODES 20000
#define N_EDGES 320000
#define H 256
#define GH 512
#define G3 768
#define NT 3
#define R_ROUNDS 2
#define MT2 79      // ceil(20000/256)
#define XW 768      // X row width (msg 512 | hv 256)
#define PW 1024     // P row width (S_rz 512 | inn 256 | hn 256)

typedef __attribute__((ext_vector_type(8))) short short8;
typedef __attribute__((ext_vector_type(8))) unsigned short ushort8;
typedef __attribute__((ext_vector_type(4))) float floatx4;

static __device__ __forceinline__ unsigned short f2bf(float x) {
  unsigned u = __float_as_uint(x);
  u += 0x7fffu + ((u >> 16) & 1u);
  return (unsigned short)(u >> 16);
}
static __device__ __forceinline__ float b2f(unsigned short x) {
  return __uint_as_float((unsigned)x << 16);
}

// async global->LDS, 16B per lane; LDS dest = wave-uniform base + lane*16
static __device__ __forceinline__ void load_lds_16(const unsigned short* g,
                                                   unsigned short* l) {
  __builtin_amdgcn_global_load_lds(
      (const __attribute__((address_space(1))) unsigned int*)g,
      (__attribute__((address_space(3))) unsigned int*)l, 16, 0, 0);
}

// ---------------------------------------------------------------- fused prep
// One launch: hv0->bf16; w_hh->bf16 (+ pack Wrz[:,512:768]); zero
// cnt/hesum/U/G/gembed; vec_comb (both rounds).
#define PB_HV 2500   // 5,120,000 elems / 2048
#define PB_WHH 192   // 393,216 elems / 2048
#define PB_CNT 10
#define PB_HES 10
#define PB_BASE (PB_HV + PB_WHH + PB_CNT + PB_HES)
#define PB_VEC 384   // 2*G3/4
#define PREP_GRID (PB_BASE + 2 + PB_VEC)

__global__ __launch_bounds__(256) void prep_kernel(
    const float* __restrict__ hv0, const float* __restrict__ w_hh,
    unsigned short* __restrict__ HVb, unsigned short* __restrict__ whhb,
    unsigned short* __restrict__ Wrz, int* __restrict__ cnt,
    float* __restrict__ hesum, float* __restrict__ U, float* __restrict__ ge,
    const float* __restrict__ msg_w, const float* __restrict__ msg_b,
    const float* __restrict__ w_ih, float* __restrict__ wep,
    float* __restrict__ bmp) {
  int b = blockIdx.x, tid = threadIdx.x;
  if (b < PB_HV) {
    int idx = (b * 256 + tid) * 8;
    const float* p = hv0 + idx;
    float4 v0 = *(const float4*)p;
    float4 v1 = *(const float4*)(p + 4);
    ushort8 o;
    o[0] = f2bf(v0.x); o[1] = f2bf(v0.y); o[2] = f2bf(v0.z); o[3] = f2bf(v0.w);
    o[4] = f2bf(v1.x); o[5] = f2bf(v1.y); o[6] = f2bf(v1.z); o[7] = f2bf(v1.w);
    *(ushort8*)(HVb + idx) = o;
  } else if (b < PB_HV + PB_WHH) {
    int idx = ((b - PB_HV) * 256 + tid) * 8;
    const float* p = w_hh + idx;
    float4 v0 = *(const float4*)p;
    float4 v1 = *(const float4*)(p + 4);
    ushort8 o;
    o[0] = f2bf(v0.x); o[1] = f2bf(v0.y); o[2] = f2bf(v0.z); o[3] = f2bf(v0.w);
    o[4] = f2bf(v1.x); o[5] = f2bf(v1.y); o[6] = f2bf(v1.z); o[7] = f2bf(v1.w);
    *(ushort8*)(whhb + idx) = o;
    int t = idx / (G3 * H);
    int rem = idx % (G3 * H);
    int n = rem / H, k = rem % H;  // 8-elem chunk stays within one row (H%8==0)
    if (n < 512)
      *(ushort8*)(Wrz + (size_t)t * 512 * XW + (size_t)n * XW + GH + k) = o;
  } else if (b < PB_HV + PB_WHH + PB_CNT) {
    int idx = ((b - PB_HV - PB_WHH) * 256 + tid) * 8;
#pragma unroll
    for (int j = 0; j < 8; j++)
      if (idx + j < N_NODES) cnt[idx + j] = 0;
  } else if (b < PB_BASE) {
    int idx = ((b - PB_HV - PB_WHH - PB_CNT) * 256 + tid) * 8;
#pragma unroll
    for (int j = 0; j < 8; j++)
      if (idx + j < N_NODES) hesum[idx + j] = 0.f;
  } else if (b == PB_BASE) {
    for (int i = tid; i < NT * H + NT; i += 256) U[i] = 0.f;
  } else if (b == PB_BASE + 1) {
    for (int i = tid; i < GH + 4 + H + 1; i += 256) ge[i] = 0.f;
  } else {
    // vec_comb: wep[ng]=dot(msg_w row512, w_ih[n]); bmp[ng]=dot(msg_b, w_ih[n])
    int vb = b - (PB_BASE + 2);
    int ng = vb * 4 + (tid >> 6);
    int t = ng / G3, n = ng % G3;
    int lane = tid & 63;
    const float* we = msg_w + (size_t)t * 513 * 512 + (size_t)GH * GH;
    const float* mb = msg_b + (size_t)t * GH;
    const float* wr = w_ih + (size_t)t * G3 * GH + (size_t)n * GH;
    float s1 = 0.f, s2 = 0.f;
    for (int k = lane; k < GH; k += 64) {
      float w = wr[k];
      s1 += we[k] * w;
      s2 += mb[k] * w;
    }
    for (int off = 32; off; off >>= 1) {
      s1 += __shfl_xor(s1, off);
      s2 += __shfl_xor(s2, off);
    }
    if (lane == 0) {
      wep[ng] = s1;
      bmp[ng] = s2;
    }
  }
}

// ---------------------------------------------------------------- CSR build
__global__ __launch_bounds__(256) void hist_kernel(
    const int* __restrict__ dst, const float* __restrict__ he,
    int* __restrict__ cnt, float* __restrict__ hesum) {
  int e = blockIdx.x * 256 + threadIdx.x;
  if (e >= N_EDGES) return;
  int d = dst[e];
  atomicAdd(&cnt[d], 1);
  unsafeAtomicAdd(&hesum[d], he[e]);
}

__global__ __launch_bounds__(1024) void scan_kernel(
    const int* __restrict__ cnt, int* __restrict__ rowptr, int* __restrict__ cursor) {
  __shared__ int part[1024];
  const int CH = (N_NODES + 1023) / 1024;  // 20
  int t = threadIdx.x;
  int base = t * CH;
  int s = 0;
  for (int j = 0; j < CH; j++) {
    int idx = base + j;
    if (idx < N_NODES) s += cnt[idx];
  }
  part[t] = s;
  __syncthreads();
  int v = part[t];
  for (int off = 1; off < 1024; off <<= 1) {
    int o = (t >= off) ? part[t - off] : 0;
    __syncthreads();
    part[t] += o;
    __syncthreads();
  }
  int excl = part[t] - v;
  int run = excl;
  for (int j = 0; j < CH; j++) {
    int idx = base + j;
    if (idx < N_NODES) {
      rowptr[idx] = run;
      cursor[idx] = run;
      run += cnt[idx];
    }
  }
  if (t == 1023) rowptr[N_NODES] = run;
}

__global__ __launch_bounds__(256) void fill_kernel(
    const int* __restrict__ dst, const int* __restrict__ src,
    int* __restrict__ cursor, int* __restrict__ nbr) {
  int e = blockIdx.x * 256 + threadIdx.x;
  if (e >= N_EDGES) return;
  int p = atomicAdd(&cursor[dst[e]], 1);
  nbr[p] = src[e];
}

// ---------------------------------------------------------------- gather (bf16 reads)
// 16B/lane reads: half-wave (32 lanes) per neighbor row, 2 neighbors in flight.
// Halves combined at the end via shfl_xor(32).
__global__ __launch_bounds__(256) void gather_kernel(
    const unsigned short* __restrict__ hvb, const int* __restrict__ rowptr,
    const int* __restrict__ nbr, unsigned short* __restrict__ X,
    float* __restrict__ deg) {
  int w = (blockIdx.x * blockDim.x + threadIdx.x) >> 6;
  int lane = threadIdx.x & 63;
  if (w >= N_NODES) return;
  int half = lane >> 5, cl = lane & 31;
  int start = rowptr[w], end = rowptr[w + 1];
  float a[8];
#pragma unroll
  for (int k = 0; k < 8; k++) a[k] = 0.f;
  for (int b = start; b < end; b += 64) {
    int nb = min(64, end - b);
    int sidx = (lane < nb) ? nbr[b + lane] : 0;
    int j = 0;
    for (; j + 8 <= nb; j += 8) {  // 8 neighbors per iter, 4 loads per lane
      ushort8 u[4];
#pragma unroll
      for (int q = 0; q < 4; q++) {
        int s = __shfl(sidx, j + 2 * q + half);
        u[q] = *reinterpret_cast<const ushort8*>(hvb + (size_t)s * H + cl * 8);
      }
#pragma unroll
      for (int q = 0; q < 4; q++)
#pragma unroll
        for (int k = 0; k < 8; k++) a[k] += b2f(u[q][k]);
    }
    for (; j + 2 <= nb; j += 2) {
      int s = __shfl(sidx, j + half);
      ushort8 u = *reinterpret_cast<const ushort8*>(hvb + (size_t)s * H + cl * 8);
#pragma unroll
      for (int k = 0; k < 8; k++) a[k] += b2f(u[k]);
    }
    if (j < nb) {  // odd tail: low half only
      int s = __shfl(sidx, j);
      if (half == 0) {
        ushort8 u = *reinterpret_cast<const ushort8*>(hvb + (size_t)s * H + cl * 8);
#pragma unroll
        for (int k = 0; k < 8; k++) a[k] += b2f(u[k]);
      }
    }
  }
#pragma unroll
  for (int k = 0; k < 8; k++) a[k] += __shfl_xor(a[k], 32);
  float dg = (float)(end - start);
  ushort4 uo = *reinterpret_cast<const ushort4*>(hvb + (size_t)w * H + lane * 4);
  ushort4 o;
  o.x = f2bf(b2f(uo.x) * dg); o.y = f2bf(b2f(uo.y) * dg);
  o.z = f2bf(b2f(uo.z) * dg); o.w = f2bf(b2f(uo.w) * dg);
  *reinterpret_cast<ushort4*>(X + (size_t)w * XW + lane * 4) = o;
  *reinterpret_cast<ushort4*>(X + (size_t)w * XW + GH + lane * 4) = uo;
  if (half == 0) {
    ushort8 on;
#pragma unroll
    for (int k = 0; k < 8; k++) on[k] = f2bf(a[k]);
    *reinterpret_cast<ushort8*>(X + (size_t)w * XW + H + cl * 8) = on;
  }
  if (lane == 0) deg[w] = dg;
}

// ---------------------------------------------------------------- GEMM pieces
// XOR chunk layout (v0): LDS[row][p] holds global chunk (p ^ (row&7)) of row.
#define MFMA_BLOCK                                                                \
  _Pragma("unroll") for (int kk = 0; kk < 2; kk++) {                              \
    short8 af[4], bf[4];                                                          \
    _Pragma("unroll") for (int mi = 0; mi < 4; mi++) {                            \
      int row = m0 + mi * 16 + lr;                                                \
      af[mi] = *(const short8*)(As + row * 64 + ((kk * 4 + lq) ^ (row & 7)) * 8); \
    }                                                                             \
    _Pragma("unroll") for (int ni = 0; ni < 4; ni++) {                            \
      int row = n0 + ni * 16 + lr;                                                \
      bf[ni] = *(const short8*)(Bs + row * 64 + ((kk * 4 + lq) ^ (row & 7)) * 8); \
    }                                                                             \
    _Pragma("unroll") for (int mi = 0; mi < 4; mi++)                              \
      _Pragma("unroll") for (int ni = 0; ni < 4; ni++)                            \
        acc[mi][ni] = __builtin_amdgcn_mfma_f32_16x16x32_bf16(af[mi], bf[ni],     \
                                                              acc[mi][ni], 0, 0, 0); \
  }

// 8-wave staging: A-tile 256x64, B-tile 128x64 (48 KB total).
static __device__ __forceinline__ void stage_tile_256(
    const unsigned short* gA, int lda, const unsigned short* gB, int ldb,
    unsigned short* As, unsigned short* Bs,
    size_t i0, size_t j0, int k0, int wv, int lane) {
  int rsub = lane >> 3;
  int pos = lane & 7;
#pragma unroll
  for (int q = 0; q < 4; q++) {
    int row = wv * 32 + q * 8 + rsub;
    int gc = (pos ^ (row & 7)) * 8;
    load_lds_16(gA + (i0 + row) * (size_t)lda + k0 + gc, As + (wv * 32 + q * 8) * 64);
  }
#pragma unroll
  for (int q = 0; q < 2; q++) {
    int row = wv * 16 + q * 8 + rsub;
    int gc = (pos ^ (row & 7)) * 8;
    load_lds_16(gB + (j0 + row) * (size_t)ldb + k0 + gc, Bs + (wv * 16 + q * 8) * 64);
  }
}

#define GEMM_CORE_256(A, lda, W, ldb, K)                                          \
  {                                                                               \
    stage_tile_256((A), (lda), (W), (ldb), As, Bs, i0, j0, 0, wv, lane);          \
    for (int k0 = 0; k0 < (K); k0 += 64) {                                        \
      __syncthreads();                                                            \
      MFMA_BLOCK                                                                  \
      if (k0 + 64 < (K)) {                                                        \
        __syncthreads();                                                          \
        stage_tile_256((A), (lda), (W), (ldb), As, Bs, i0, j0, k0 + 64, wv, lane);\
      }                                                                           \
    }                                                                             \
  }

// ---------------------------------------------------------------- weight-combine GEMM
static __device__ __forceinline__ void wstage_f32(
    const float* gA, const float* gB, unsigned short* As, unsigned short* Bs,
    size_t i0, size_t j0, int k0, int wv, int lane) {
  int rsub = lane >> 3;
  int pos = lane & 7;
#pragma unroll
  for (int q = 0; q < 4; q++) {
    int row = wv * 32 + q * 8 + rsub;
    int gc = (pos ^ (row & 7)) * 8;
    const float* pa = gA + (i0 + row) * (size_t)GH + k0 + gc;
    const float* pb = gB + (j0 + row) * (size_t)GH + k0 + gc;
    float4 a0 = *(const float4*)pa;
    float4 a1 = *(const float4*)(pa + 4);
    float4 b0 = *(const float4*)pb;
    float4 b1 = *(const float4*)(pb + 4);
    ushort8 ua, ub;
    ua[0] = f2bf(a0.x); ua[1] = f2bf(a0.y); ua[2] = f2bf(a0.z); ua[3] = f2bf(a0.w);
    ua[4] = f2bf(a1.x); ua[5] = f2bf(a1.y); ua[6] = f2bf(a1.z); ua[7] = f2bf(a1.w);
    ub[0] = f2bf(b0.x); ub[1] = f2bf(b0.y); ub[2] = f2bf(b0.z); ub[3] = f2bf(b0.w);
    ub[4] = f2bf(b1.x); ub[5] = f2bf(b1.y); ub[6] = f2bf(b1.z); ub[7] = f2bf(b1.w);
    *(ushort8*)(As + row * 64 + pos * 8) = ua;
    *(ushort8*)(Bs + row * 64 + pos * 8) = ub;
  }
}

__global__ __launch_bounds__(256) void wcomb_gemm(
    const float* __restrict__ w_ih, const float* __restrict__ msg_w,
    unsigned short* __restrict__ Wc, unsigned short* __restrict__ Wrz) {
  __shared__ alignas(16) unsigned short As[128 * 64];
  __shared__ alignas(16) unsigned short Bs[128 * 64];
  int t = threadIdx.x;
  int rt = blockIdx.z;
  const float* A = w_ih + (size_t)rt * G3 * GH;
  const float* W = msg_w + (size_t)rt * 513 * 512;
  unsigned short* Cb = Wc + (size_t)rt * G3 * GH;
  unsigned short* Rz = Wrz + (size_t)rt * 512 * XW;
  size_t i0 = (size_t)blockIdx.y * 128;
  size_t j0 = (size_t)blockIdx.x * 128;
  int wv = t >> 6, lane = t & 63;
  int m0 = (wv >> 1) * 64, n0 = (wv & 1) * 64;
  int lr = lane & 15, lq = lane >> 4;
  floatx4 acc[4][4];
#pragma unroll
  for (int a = 0; a < 4; a++)
#pragma unroll
    for (int b = 0; b < 4; b++) acc[a][b] = (floatx4){0.f, 0.f, 0.f, 0.f};
  {
    wstage_f32(A, W, As, Bs, i0, j0, 0, wv, lane);
    for (int k0 = 0; k0 < GH; k0 += 64) {
      __syncthreads();
      MFMA_BLOCK
      if (k0 + 64 < GH) {
        __syncthreads();
        wstage_f32(A, W, As, Bs, i0, j0, k0 + 64, wv, lane);
      }
    }
  }
#pragma unroll
  for (int mi = 0; mi < 4; mi++) {
#pragma unroll
    for (int ni = 0; ni < 4; ni++) {
      int col = (int)j0 + n0 + ni * 16 + lr;
#pragma unroll
      for (int i = 0; i < 4; i++) {
        size_t row = i0 + m0 + mi * 16 + lq * 4 + i;
        unsigned short v = f2bf(acc[mi][ni][i]);
        Cb[row * GH + col] = v;
        if (row < 512) Rz[row * XW + col] = v;
      }
    }
  }
}

// ---------------------------------------------------------------- fused gate GEMM
// BM=256 x BN=128, 8 waves (512 thr), 48 KB LDS, proven 2-barrier schedule.
__global__ __launch_bounds__(512) void gate_gemm(
    const unsigned short* __restrict__ X, const unsigned short* __restrict__ Wrz,
    const unsigned short* __restrict__ Wc_t, const unsigned short* __restrict__ Whh_t,
    const float* __restrict__ wep, const float* __restrict__ bmp,
    const float* __restrict__ bih, const float* __restrict__ bhh,
    const float* __restrict__ deg, const float* __restrict__ hesum,
    unsigned short* __restrict__ P) {
  __shared__ alignas(16) unsigned short As[256 * 64];
  __shared__ alignas(16) unsigned short Bs[128 * 64];
  int bid = blockIdx.x;
  int xk = bid & 7, sl = bid >> 3;  // sl in [0,80)
  int it = xk * 10 + (sl >> 3);
  if (it >= MT2) return;
  int jb = sl & 7;
  int t = threadIdx.x;
  size_t i0 = (size_t)it * 256;
  size_t j0 = 0;
  int wv = t >> 6, lane = t & 63;
  int m0 = (wv >> 1) * 64, n0 = (wv & 1) * 64;
  int lr = lane & 15, lq = lane >> 4;
  floatx4 acc[4][4];
#pragma unroll
  for (int a = 0; a < 4; a++)
#pragma unroll
    for (int b = 0; b < 4; b++) acc[a][b] = (floatx4){0.f, 0.f, 0.f, 0.f};

  const unsigned short* Abase;
  const unsigned short* Bbase;
  int K, ldb, ocol0;
  if (jb < 4) {
    Abase = X; K = XW; Bbase = Wrz + (size_t)(jb * 128) * XW; ldb = XW;
    ocol0 = jb * 128;
  } else if (jb < 6) {
    Abase = X; K = GH; Bbase = Wc_t + (size_t)(512 + (jb - 4) * 128) * GH; ldb = GH;
    ocol0 = 512 + (jb - 4) * 128;
  } else {
    Abase = X + GH; K = H; Bbase = Whh_t + (size_t)(512 + (jb - 6) * 128) * H; ldb = H;
    ocol0 = 768 + (jb - 6) * 128;
  }
  GEMM_CORE_256(Abase, XW, Bbase, ldb, K)

  bool add_gi = (jb < 6);
  bool add_hh = (jb < 4) || (jb >= 6);
  int g3base = (jb >= 6) ? (ocol0 - 256) : ocol0;
#pragma unroll
  for (int mi = 0; mi < 4; mi++) {
#pragma unroll
    for (int ni = 0; ni < 4; ni++) {
      int oc = ocol0 + n0 + ni * 16 + lr;
      int gc = g3base + n0 + ni * 16 + lr;
      float badd = 0.f, wv_ = 0.f, bv = 0.f;
      if (add_gi) { badd += bih[gc]; wv_ = wep[gc]; bv = bmp[gc]; }
      if (add_hh) badd += bhh[gc];
#pragma unroll
      for (int i = 0; i < 4; i++) {
        size_t row = i0 + m0 + mi * 16 + lq * 4 + i;
        if (row < (size_t)N_NODES)
          P[row * PW + oc] =
              f2bf(acc[mi][ni][i] + hesum[row] * wv_ + deg[row] * bv + badd);
      }
    }
  }
}

// ---------------------------------------------------------------- GRU elementwise
// On the final round also computes gate sigmoid + dest scores from hvv in-reg.
__global__ __launch_bounds__(256) void gru_update(
    const unsigned short* __restrict__ P, const float* __restrict__ hvin,
    float* __restrict__ hvout, unsigned short* __restrict__ hvb, int do_heads,
    const int* __restrict__ ntype, const float* __restrict__ gate_w,
    const float* __restrict__ gate_b, const float* __restrict__ dest_w,
    float* __restrict__ gw, float* __restrict__ scores) {
  int idx = blockIdx.x * 256 + threadIdx.x;
  if (idx >= N_NODES * 32) return;
  int row = idx >> 5;
  int c8 = (idx & 31) << 3;
  const unsigned short* pr = P + (size_t)row * PW;
  ushort8 vsr = *(const ushort8*)(pr + c8);
  ushort8 vsz = *(const ushort8*)(pr + 256 + c8);
  ushort8 vin = *(const ushort8*)(pr + 512 + c8);
  ushort8 vhn = *(const ushort8*)(pr + 768 + c8);
  const float* hp = hvin + (size_t)row * H + c8;
  float4 h0 = *(const float4*)hp;
  float4 h1 = *(const float4*)(hp + 4);
  float hvv[8] = {h0.x, h0.y, h0.z, h0.w, h1.x, h1.y, h1.z, h1.w};
  ushort8 ob;
#pragma unroll
  for (int j = 0; j < 8; j++) {
    float r = 1.f / (1.f + expf(-b2f(vsr[j])));
    float z = 1.f / (1.f + expf(-b2f(vsz[j])));
    float n = tanhf(b2f(vin[j]) + r * b2f(vhn[j]));
    hvv[j] = (1.f - z) * n + z * hvv[j];
    ob[j] = f2bf(hvv[j]);
  }
  float* op = hvout + (size_t)row * H + c8;
  *(float4*)op = make_float4(hvv[0], hvv[1], hvv[2], hvv[3]);
  *(float4*)(op + 4) = make_float4(hvv[4], hvv[5], hvv[6], hvv[7]);
  *(ushort8*)(hvb + (size_t)row * H + c8) = ob;
  if (do_heads) {
    int tg = ntype[row];
    const float* gwp = gate_w + tg * H + c8;
    const float* dwp = dest_w + c8;
    float sg = 0.f, sd = 0.f;
#pragma unroll
    for (int j = 0; j < 8; j++) {
      sg += hvv[j] * gwp[j];
      sd += hvv[j] * dwp[j];
    }
    for (int off = 16; off; off >>= 1) {
      sg += __shfl_xor(sg, off);
      sd += __shfl_xor(sd, off);
    }
    if ((threadIdx.x & 31) == 0) {
      gw[row] = 1.f / (1.f + expf(-(sg + gate_b[tg])));
      if (row < N_NODES - 1) scores[row] = sd;
    }
  }
}

// ---------------------------------------------------------------- U column-sum
__global__ __launch_bounds__(256) void usum_kernel(
    const float* __restrict__ hv, const int* __restrict__ ntype,
    const float* __restrict__ gw, float* __restrict__ U, float* __restrict__ G) {
  const int CH = (N_NODES + 255) / 256;  // 79
  int col = threadIdx.x;
  int r0 = blockIdx.x * CH;
  int r1 = min(r0 + CH, N_NODES);
  float a0 = 0.f, a1 = 0.f, a2 = 0.f;
  float g0 = 0.f, g1 = 0.f, g2 = 0.f;
  int i = r0;
  for (; i + 4 <= r1; i += 4) {
    float v0 = hv[(size_t)(i + 0) * H + col];
    float v1 = hv[(size_t)(i + 1) * H + col];
    float v2 = hv[(size_t)(i + 2) * H + col];
    float v3 = hv[(size_t)(i + 3) * H + col];
    int t0 = ntype[i + 0], t1 = ntype[i + 1], t2 = ntype[i + 2], t3 = ntype[i + 3];
    float w0 = gw[i + 0], w1 = gw[i + 1], w2 = gw[i + 2], w3 = gw[i + 3];
    v0 *= w0; v1 *= w1; v2 *= w2; v3 *= w3;
    a0 += (t0 == 0) ? v0 : 0.f; a1 += (t0 == 1) ? v0 : 0.f; a2 += (t0 == 2) ? v0 : 0.f;
    a0 += (t1 == 0) ? v1 : 0.f; a1 += (t1 == 1) ? v1 : 0.f; a2 += (t1 == 2) ? v1 : 0.f;
    a0 += (t2 == 0) ? v2 : 0.f; a1 += (t2 == 1) ? v2 : 0.f; a2 += (t2 == 2) ? v2 : 0.f;
    a0 += (t3 == 0) ? v3 : 0.f; a1 += (t3 == 1) ? v3 : 0.f; a2 += (t3 == 2) ? v3 : 0.f;
    g0 += (t0 == 0) ? w0 : 0.f; g1 += (t0 == 1) ? w0 : 0.f; g2 += (t0 == 2) ? w0 : 0.f;
    g0 += (t1 == 0) ? w1 : 0.f; g1 += (t1 == 1) ? w1 : 0.f; g2 += (t1 == 2) ? w1 : 0.f;
    g0 += (t2 == 0) ? w2 : 0.f; g1 += (t2 == 1) ? w2 : 0.f; g2 += (t2 == 2) ? w2 : 0.f;
    g0 += (t3 == 0) ? w3 : 0.f; g1 += (t3 == 1) ? w3 : 0.f; g2 += (t3 == 2) ? w3 : 0.f;
  }
  for (; i < r1; i++) {
    float v = hv[(size_t)i * H + col];
    int t = ntype[i];
    float w = gw[i];
    v *= w;
    a0 += (t == 0) ? v : 0.f; a1 += (t == 1) ? v : 0.f; a2 += (t == 2) ? v : 0.f;
    g0 += (t == 0) ? w : 0.f; g1 += (t == 1) ? w : 0.f; g2 += (t == 2) ? w : 0.f;
  }
  unsafeAtomicAdd(&U[0 * H + col], a0);
  unsafeAtomicAdd(&U[1 * H + col], a1);
  unsafeAtomicAdd(&U[2 * H + col], a2);
  if (col == 0) {
    unsafeAtomicAdd(&G[0], g0);
    unsafeAtomicAdd(&G[1], g1);
    unsafeAtomicAdd(&G[2], g2);
  }
}

// ---------------------------------------------------------------- gembed (k-split, MLP)
__global__ __launch_bounds__(256) void gembed_partial(
    const float* __restrict__ U, const float* __restrict__ G,
    const float* __restrict__ tograph_w, const float* __restrict__ tograph_b,
    float* __restrict__ gembed_out) {
  int b = blockIdx.x;
  int t = b >> 4, half = (b >> 3) & 1, kc = b & 7;
  int col = half * 256 + threadIdx.x;
  int k0 = kc * 32;
  const float* Wt = tograph_w + (size_t)t * H * GH;
  float w[32], u[32];
#pragma unroll
  for (int j = 0; j < 32; j++) w[j] = Wt[(size_t)(k0 + j) * GH + col];
#pragma unroll
  for (int j = 0; j < 32; j++) u[j] = U[t * H + k0 + j];
  float acc = (kc == 0) ? G[t] * tograph_b[t * GH + col] : 0.f;
#pragma unroll
  for (int j = 0; j < 32; j++) acc += u[j] * w[j];
  unsafeAtomicAdd(&gembed_out[col], acc);
}

// ---------------------------------------------------------------- heads (k-split, MLP)
__global__ __launch_bounds__(256) void heads_kernel(
    const float* __restrict__ ge, const float* __restrict__ addnode_w,
    const float* __restrict__ addnode_b, const float* __restrict__ ntype_embed,
    const float* __restrict__ inithv_w, const float* __restrict__ inithv_b,
    const float* __restrict__ addedge_w, const float* __restrict__ addedge_b,
    const float* __restrict__ hv, float* __restrict__ nodelogp_out,
    float* __restrict__ hvinit_out, float* __restrict__ edgelogit_out) {
  int b = blockIdx.x;
  int tid = threadIdx.x;
  if (b < 24) {
    int k0 = b * 32;
    float w[32], x[32];
#pragma unroll
    for (int j = 0; j < 32; j++) w[j] = inithv_w[(size_t)(k0 + j) * H + tid];
#pragma unroll
    for (int j = 0; j < 32; j++) {
      int k = k0 + j;
      x[j] = (k < H) ? ntype_embed[k] : ge[k - H];
    }
    float acc = (b == 0) ? inithv_b[tid] : 0.f;
#pragma unroll
    for (int j = 0; j < 32; j++) acc += x[j] * w[j];
    unsafeAtomicAdd(&hvinit_out[tid], acc);
  } else if (b == 24) {
    __shared__ float lg[4];
    int w = tid >> 6, lane = tid & 63;
    float s = 0.f;
    for (int k = lane; k < GH; k += 64) s += ge[k] * addnode_w[k * 4 + w];
    for (int off = 32; off; off >>= 1) s += __shfl_xor(s, off);
    if (lane == 0) lg[w] = s + addnode_b[w];
    __syncthreads();
    if (tid == 0) {
      float m = fmaxf(fmaxf(lg[0], lg[1]), fmaxf(lg[2], lg[3]));
      float sum = 0.f;
      for (int c = 0; c < 4; c++) sum += expf(lg[c] - m);
      float lse = m + logf(sum);
      for (int c = 0; c < 4; c++) nodelogp_out[c] = lg[c] - lse;
    }
  } else {
    int w = tid >> 6, lane = tid & 63;
    if (w == 0) {
      const float* se = hv + (size_t)(N_NODES - 1) * H;
      float s = 0.f;
      for (int k = lane; k < G3; k += 64) {
        float x = (k < GH) ? ge[k] : se[k - GH];
        s += x * addedge_w[k];
      }
      for (int off = 32; off; off >>= 1) s += __shfl_xor(s, off);
      if (lane == 0) edgelogit_out[0] = s + addedge_b[0];
    }
  }
}

__global__ __launch_bounds__(1024) void dest_softmax(const float* __restrict__ scores,
                                                     float* __restrict__ out) {
  const int n = N_NODES - 1;
  __shared__ float red[16];
  __shared__ float bc[2];
  int tid = threadIdx.x;
  float m = -1e30f;
  for (int i = tid; i < n; i += 1024) m = fmaxf(m, scores[i]);
  for (int off = 32; off; off >>= 1) m = fmaxf(m, __shfl_xor(m, off));
  if ((tid & 63) == 0) red[tid >> 6] = m;
  __syncthreads();
  if (tid == 0) {
    float v = red[0];
    for (int i = 1; i < 16; i++) v = fmaxf(v, red[i]);
    bc[0] = v;
  }
  __syncthreads();
  float mx = bc[0];
  float s = 0.f;
  for (int i = tid; i < n; i += 1024) s += expf(scores[i] - mx);
  for (int off = 32; off; off >>= 1) s += __shfl_xor(s, off);
  if ((tid & 63) == 0) red[tid >> 6] = s;
  __syncthreads();
  if (tid == 0) {
    float v = 0.f;
    for (int i = 0; i < 16; i++) v += red[i];
    bc[1] = v;
  }
  __syncthreads();
  float lse = mx + logf(bc[1]);
  for (int i = tid; i < n; i += 1024) out[i] = scores[i] - lse;
}

// ---------------------------------------------------------------- launch
extern "C" void kernel_launch(void* const* d_in, const int* in_sizes, int n_in,
                              void* d_out, int out_size, void* d_ws, size_t ws_size,
                              hipStream_t stream) {
  const float* hv0 = (const float*)d_in[0];
  const float* he = (const float*)d_in[1];
  const int* ntype = (const int*)d_in[2];
  const int* src = (const int*)d_in[3];
  const int* dst = (const int*)d_in[4];
  const float* msg_w = (const float*)d_in[5];
  const float* msg_b = (const float*)d_in[6];
  const float* w_ih = (const float*)d_in[7];
  const float* b_ih = (const float*)d_in[8];
  const float* w_hh = (const float*)d_in[9];
  const float* b_hh = (const float*)d_in[10];
  const float* gate_w = (const float*)d_in[11];
  const float* gate_b = (const float*)d_in[12];
  const float* tograph_w = (const float*)d_in[13];
  const float* tograph_b = (const float*)d_in[14];
  const float* addnode_w = (const float*)d_in[15];
  const float* addnode_b = (const float*)d_in[16];
  const float* ntype_embed = (const float*)d_in[17];
  const float* inithv_w = (const float*)d_in[18];
  const float* inithv_b = (const float*)d_in[19];
  const float* addedge_w = (const float*)d_in[20];
  const float* addedge_b = (const float*)d_in[21];
  const float* dest_w = (const float*)d_in[22];
  const float* dest_b = (const float*)d_in[23];

  float* out = (float*)d_out;
  float* HV = out;
  float* gembed_out = out + (size_t)N_NODES * H;
  float* nodelogp_out = gembed_out + GH;
  float* hvinit_out = nodelogp_out + 4;
  float* edgelogit_out = hvinit_out + H;
  float* destlogp_out = edgelogit_out + 1;

  float* ws = (float*)d_ws;
  float* deg = ws;                                    // N
  float* hesum = deg + N_NODES;                       // N
  float* U = hesum + N_NODES;                         // NT*H
  float* G = U + NT * H;                              // NT
  float* misc = G + NT;                               // 16
  float* wep = misc + 16;                             // 2*G3
  float* bmp = wep + 2 * G3;                          // 2*G3
  float* scores = bmp + 2 * G3;                       // N
  float* gw = scores + N_NODES;                       // N
  int* cnt = (int*)(gw + N_NODES);                    // N
  int* rowptr = cnt + N_NODES;                        // N+1
  int* cursor = rowptr + N_NODES + 1;                 // N
  int* nbr = cursor + N_NODES;                        // E
  unsigned short* X =
      (unsigned short*)(((uintptr_t)(nbr + N_EDGES) + 15) & ~(uintptr_t)15);
  unsigned short* P = X + (size_t)(N_NODES + 256) * XW;  // X padded for BM=256 tail
  unsigned short* HVb = P + (size_t)(N_NODES + 128) * PW;
  unsigned short* whhb = HVb + (size_t)(N_NODES + 128) * H;
  unsigned short* Wc = whhb + (size_t)2 * G3 * H;      // 2 * G3*GH
  unsigned short* Wrz = Wc + (size_t)2 * G3 * GH;      // 2 * 512*768

  // ---- fused prep: casts + pack + zeroing + vec_comb
  prep_kernel<<<PREP_GRID, 256, 0, stream>>>(hv0, w_hh, HVb, whhb, Wrz, cnt,
                                             hesum, U, gembed_out, msg_w, msg_b,
                                             w_ih, wep, bmp);
  // weight-combine (reads f32 directly, both rounds in one launch)
  wcomb_gemm<<<dim3(GH / 128, G3 / 128, 2), 256, 0, stream>>>(w_ih, msg_w, Wc, Wrz);

  // ---- CSR build
  hist_kernel<<<(N_EDGES + 255) / 256, 256, 0, stream>>>(dst, he, cnt, hesum);
  scan_kernel<<<1, 1024, 0, stream>>>(cnt, rowptr, cursor);
  fill_kernel<<<(N_EDGES + 255) / 256, 256, 0, stream>>>(dst, src, cursor, nbr);

  for (int t = 0; t < R_ROUNDS; t++) {
    gather_kernel<<<N_NODES / 4, 256, 0, stream>>>(HVb, rowptr, nbr, X, deg);
    gate_gemm<<<640, 512, 0, stream>>>(
        X, Wrz + (size_t)t * 512 * XW, Wc + (size_t)t * G3 * GH,
        whhb + (size_t)t * G3 * H, wep + (size_t)t * G3, bmp + (size_t)t * G3,
        b_ih + (size_t)t * G3, b_hh + (size_t)t * G3, deg, hesum, P);
    gru_update<<<(N_NODES * 32 + 255) / 256, 256, 0, stream>>>(
        P, (t == 0) ? hv0 : HV, HV, HVb, (t == R_ROUNDS - 1) ? 1 : 0, ntype,
        gate_w, gate_b, dest_w, gw, scores);
  }

  // dest softmax (dedicated 1024-thread block — 4x the parallelism of the fold)
  dest_softmax<<<1, 1024, 0, stream>>>(scores, destlogp_out);

  // ---- graph embed + heads
  usum_kernel<<<256, 256, 0, stream>>>(HV, ntype, gw, U, G);
  gembed_partial<<<48, 256, 0, stream>>>(U, G, tograph_w, tograph_b, gembed_out);
  heads_kernel<<<26, 256, 0, stream>>>(gembed_out, addnode_w, addnode_b, ntype_embed,
                                       inithv_w, inithv_b, addedge_w, addedge_b, HV,
                                       nodelogp_out, hvinit_out, edgelogit_out);
}